// Round 5
// baseline (478.631 us; speedup 1.0000x reference)
//
#include <hip/hip_runtime.h>
#include <hip/hip_bf16.h>
#include <cstdint>
#include <cstddef>

// SlabAttention on MI355X (gfx950).
// Stage 0: convert x, qkv_w, proj_w to bf16
// Stage 1: qkv = x @ qkv_w^T  (bf16 MFMA, 256x128 tiles, global_load_lds)
// Stage 2: kv_part[bh,4] = k^T v via MFMA 32x32x16 (no atomics)
// Stage 3: out_pre = (q@kv)*z + dwconv5x5(v) + b -> (B,N,C) bf16
//          attention via MFMA (kv,ksum as bf16 B-frags), conv via VALU->LDS
// Stage 4: out = out_pre @ proj_w^T + proj_b  (bf16 MFMA 256x128, fp32 out)

typedef __bf16 bf16;
typedef __attribute__((ext_vector_type(8))) __bf16 bf16x8;
typedef __attribute__((ext_vector_type(4))) __bf16 bf16x4;
typedef __attribute__((ext_vector_type(4))) float f32x4;
typedef __attribute__((ext_vector_type(16))) float f32x16;

#define NHEADS 12
#define HD 32
#define BATCH 16
#define SEQ 4096
#define CDIM 384
#define BHN (BATCH*NHEADS)   // 192
#define KVPARTS 4

// async global->LDS, 16 B per lane; dest must be lane-linear from wave base
__device__ __forceinline__ void gl_lds16(const bf16* g, bf16* l) {
    __builtin_amdgcn_global_load_lds(
        (const __attribute__((address_space(1))) unsigned int*)g,
        (__attribute__((address_space(3))) unsigned int*)l, 16, 0, 0);
}

// ---------------------------------------------------------------- K0: convert
__global__ void convert_in(const float* __restrict__ X, const float* __restrict__ qkvw,
                           const float* __restrict__ projw,
                           bf16* __restrict__ xb, bf16* __restrict__ qkvw_b,
                           bf16* __restrict__ projw_b) {
    int i = blockIdx.x * 256 + threadIdx.x;
    int stride = gridDim.x * 256;
    const int nx = (65536 * CDIM) / 8;
    for (int c = i; c < nx; c += stride) {
        const float* s = X + (size_t)c * 8;
        float4 f0 = *(const float4*)s;
        float4 f1 = *(const float4*)(s + 4);
        bf16x8 h;
        h[0]=(bf16)f0.x; h[1]=(bf16)f0.y; h[2]=(bf16)f0.z; h[3]=(bf16)f0.w;
        h[4]=(bf16)f1.x; h[5]=(bf16)f1.y; h[6]=(bf16)f1.z; h[7]=(bf16)f1.w;
        *(bf16x8*)&xb[(size_t)c * 8] = h;
    }
    const int nq = (3 * CDIM * CDIM) / 8;
    for (int c = i; c < nq; c += stride) {
        const float* s = qkvw + (size_t)c * 8;
        float4 f0 = *(const float4*)s;
        float4 f1 = *(const float4*)(s + 4);
        bf16x8 h;
        h[0]=(bf16)f0.x; h[1]=(bf16)f0.y; h[2]=(bf16)f0.z; h[3]=(bf16)f0.w;
        h[4]=(bf16)f1.x; h[5]=(bf16)f1.y; h[6]=(bf16)f1.z; h[7]=(bf16)f1.w;
        *(bf16x8*)&qkvw_b[(size_t)c * 8] = h;
    }
    const int np = (CDIM * CDIM) / 8;
    for (int c = i; c < np; c += stride) {
        const float* s = projw + (size_t)c * 8;
        float4 f0 = *(const float4*)s;
        float4 f1 = *(const float4*)(s + 4);
        bf16x8 h;
        h[0]=(bf16)f0.x; h[1]=(bf16)f0.y; h[2]=(bf16)f0.z; h[3]=(bf16)f0.w;
        h[4]=(bf16)f1.x; h[5]=(bf16)f1.y; h[6]=(bf16)f1.z; h[7]=(bf16)f1.w;
        *(bf16x8*)&projw_b[(size_t)c * 8] = h;
    }
}

// ---------------------------------------------------------------- K1: qkv GEMM
// 256x128 tile. A rows 0..255 and B rows 256..383 share one LDS array.
// 2304 blocks, xcd-swizzled. Wave w owns rows [w*64, w*64+64) x all 128 cols.
__global__ __launch_bounds__(256, 2)
void gemm_qkv(const bf16* __restrict__ X, const bf16* __restrict__ Wb,
              const float* __restrict__ pos,
              bf16* __restrict__ qh, bf16* __restrict__ kh, bf16* __restrict__ vh) {
    __shared__ bf16 sh[384 * 64];
    const int tid  = threadIdx.x;
    const int lane = tid & 63;
    const int wid  = tid >> 6;
    const int blk  = blockIdx.x;
    const int work = (blk & 7) * (2304 / 8) + (blk >> 3);
    const int mt   = work / 9;
    const int nt   = work - mt * 9;
    const int m0   = mt * 256;
    const int n0   = nt * 128;
    const int lr   = lane & 15;
    const int lq   = lane >> 4;
    const int srow = lane >> 3;
    const int sc   = lane & 7;

    f32x4 acc[4][8] = {};

    for (int k0 = 0; k0 < CDIM; k0 += 64) {
        #pragma unroll
        for (int it = 0; it < 12; ++it) {
            int rbase = wid * 96 + it * 8;      // wave-uniform
            int g = rbase + srow;               // 0..383
            int gc = sc ^ (g & 7);
            const bf16* src = (g < 256)
                ? &X [(size_t)(m0 + g) * CDIM + k0 + gc * 8]
                : &Wb[(size_t)(n0 + g - 256) * CDIM + k0 + gc * 8];
            gl_lds16(src, &sh[rbase * 64]);
        }
        __syncthreads();
        #pragma unroll
        for (int ks = 0; ks < 2; ++ks) {
            bf16x8 af[4], bfr[8];
            #pragma unroll
            for (int mi = 0; mi < 4; ++mi) {
                int r = wid * 64 + mi * 16 + lr;
                af[mi] = *(const bf16x8*)&sh[r * 64 + ((ks * 4 + lq) ^ (r & 7)) * 8];
            }
            #pragma unroll
            for (int ni = 0; ni < 8; ++ni) {
                int r = 256 + ni * 16 + lr;
                bfr[ni] = *(const bf16x8*)&sh[r * 64 + ((ks * 4 + lq) ^ (r & 7)) * 8];
            }
            #pragma unroll
            for (int mi = 0; mi < 4; ++mi)
                #pragma unroll
                for (int ni = 0; ni < 8; ++ni)
                    acc[mi][ni] = __builtin_amdgcn_mfma_f32_16x16x32_bf16(
                        af[mi], bfr[ni], acc[mi][ni], 0, 0, 0);
        }
        __syncthreads();
    }

    const int sec = n0 / CDIM;   // 0=q 1=k 2=v (uniform per block)
    #pragma unroll
    for (int mi = 0; mi < 4; ++mi) {
        #pragma unroll
        for (int ni = 0; ni < 8; ++ni) {
            int n = n0 + ni * 16 + lr;
            int c = n - sec * CDIM;
            int hh = c >> 5, d = c & 31;
            #pragma unroll
            for (int r = 0; r < 4; ++r) {
                int m = m0 + wid * 64 + mi * 16 + lq * 4 + r;
                int b = m >> 12, i = m & 4095;
                float v = acc[mi][ni][r];
                size_t dst = ((size_t)(b * NHEADS + hh) * SEQ + i) * HD + d;
                if (sec == 0) {
                    qh[dst] = (bf16)fmaxf(v, 0.f);
                } else if (sec == 1) {
                    v += pos[(size_t)i * CDIM + c];
                    kh[dst] = (bf16)fmaxf(v, 0.f);
                } else {
                    vh[dst] = (bf16)v;
                }
            }
        }
    }
}

// ---------------------------------------------------------------- K2: kv + ksum (MFMA)
// grid (KVPARTS, BHN), 4 waves/block, 256 rows/wave.
__global__ __launch_bounds__(256, 2)
void kv_mfma(const bf16* __restrict__ kh, const bf16* __restrict__ vh,
             float* __restrict__ kv_part, float* __restrict__ ksum_part) {
    __shared__ float red[4 * 1024];
    __shared__ float ksred[4 * 32];
    const int tid  = threadIdx.x;
    const int lane = tid & 63;
    const int w    = tid >> 6;
    const int bh   = blockIdx.y;
    const int part = blockIdx.x;
    const int col  = lane & 31;
    const int half = lane >> 5;
    const bf16* kb = kh + (size_t)bh * SEQ * HD;
    const bf16* vb = vh + (size_t)bh * SEQ * HD;
    const int j0 = part * 1024 + w * 256;

    f32x16 acc = {};
    f32x16 aks = {};
    bf16x8 ones;
    #pragma unroll
    for (int j = 0; j < 8; ++j) ones[j] = (bf16)1.0f;

    #pragma unroll 2
    for (int s = 0; s < 16; ++s) {
        int jb = j0 + s * 16 + half * 8;
        bf16x8 afr, bfr;
        #pragma unroll
        for (int j = 0; j < 8; ++j) {
            afr[j] = kb[(size_t)(jb + j) * HD + col];
            bfr[j] = vb[(size_t)(jb + j) * HD + col];
        }
        acc = __builtin_amdgcn_mfma_f32_32x32x16_bf16(afr, bfr, acc, 0, 0, 0);
        aks = __builtin_amdgcn_mfma_f32_32x32x16_bf16(afr, ones, aks, 0, 0, 0);
    }

    #pragma unroll
    for (int r = 0; r < 16; ++r) {
        int row = (r & 3) + 8 * (r >> 2) + 4 * half;
        red[w * 1024 + row * 32 + col] = acc[r];
        ksred[w * 32 + row] = aks[r];
    }
    __syncthreads();
    {
        int e = tid * 4;
        f32x4 s4 = *(f32x4*)&red[e];
        s4 += *(f32x4*)&red[1024 + e];
        s4 += *(f32x4*)&red[2048 + e];
        s4 += *(f32x4*)&red[3072 + e];
        *(f32x4*)&kv_part[((size_t)bh * KVPARTS + part) * 1024 + e] = s4;
    }
    if (tid < 32) {
        ksum_part[((size_t)bh * KVPARTS + part) * 32 + tid] =
            ksred[tid] + ksred[32 + tid] + ksred[64 + tid] + ksred[96 + tid];
    }
}

// ---------------------------------------------------------------- K3: out_pre
// grid (16, BHN): strip of 4 spatial rows = 256 tokens per block.
// Phase A: stage v halo (8 rows), kv, ksum, conv weights.
// Phase B: depthwise conv (VALU, 8 d's per thread) -> convres LDS (bf16)
// Phase C: attention via MFMA 32x32x16 (O = Q@KV, den = Q@bcast(ksum)),
//          epilogue merges convres in matching C-layout.
__global__ __launch_bounds__(256, 2)
void attn_out(const bf16* __restrict__ qh, const bf16* __restrict__ vh,
              const float* __restrict__ kv_part, const float* __restrict__ ksum_part,
              const float* __restrict__ dwcw, const float* __restrict__ dwcb,
              bf16* __restrict__ outp) {
    __shared__ bf16 vt[8 * 64 * 32];     // 32 KB halo tile (rows ys-2..ys+5)
    __shared__ bf16 convres[256 * 32];   // 16 KB
    __shared__ float kvl[1024];
    __shared__ float ksl[32];
    __shared__ float wl[25 * 32];
    __shared__ float bl[32];
    const int tid  = threadIdx.x;
    const int lane = tid & 63;
    const int wid  = tid >> 6;
    const int bh   = blockIdx.y;
    const int ys   = blockIdx.x * 4;
    const bf16* vbase = vh + (size_t)bh * SEQ * HD;
    const bf16* qbase = qh + (size_t)bh * SEQ * HD;

    // ---- Phase A: stage
    #pragma unroll
    for (int it = 0; it < 8; ++it) {
        int cid = tid + it * 256;        // 2048 chunks of 8 bf16
        int vy = cid >> 8;               // 0..7
        int xx = (cid >> 2) & 63;
        int q  = cid & 3;
        int gy = ys + vy - 2;
        bf16x8 val = {};
        if (gy >= 0 && gy < 64)
            val = *(const bf16x8*)&vbase[((size_t)gy * 64 + xx) * HD + q * 8];
        *(bf16x8*)&vt[(vy * 64 + xx) * HD + q * 8] = val;
    }
    {
        const float* kp = kv_part + (size_t)bh * KVPARTS * 1024;
        f32x4 t = *(const f32x4*)&kp[tid * 4];
        t += *(const f32x4*)&kp[1024 + tid * 4];
        t += *(const f32x4*)&kp[2048 + tid * 4];
        t += *(const f32x4*)&kp[3072 + tid * 4];
        *(f32x4*)&kvl[tid * 4] = t;
    }
    if (tid < 32) {
        const float* sp = ksum_part + (size_t)bh * KVPARTS * 32;
        ksl[tid] = sp[tid] + sp[32 + tid] + sp[64 + tid] + sp[96 + tid];
        #pragma unroll
        for (int tap = 0; tap < 25; ++tap) wl[tap * 32 + tid] = dwcw[tid * 25 + tap];
        bl[tid] = dwcb[tid];
    }
    __syncthreads();

    // ---- Phase B: conv, thread = (pixel group, 8 d's)
    {
        const int d0 = (tid & 3) * 8;
        const int ri = tid >> 2;         // 0..63
        #pragma unroll
        for (int it = 0; it < 4; ++it) {
            int pix = ri + it * 64;      // 0..255
            int yy = pix >> 6;           // 0..3
            int x  = pix & 63;
            float f[8];
            #pragma unroll
            for (int dd = 0; dd < 8; ++dd) f[dd] = bl[d0 + dd];
            int vyc = yy + 2;
            #pragma unroll
            for (int dy = -2; dy <= 2; ++dy) {
                #pragma unroll
                for (int dx = -2; dx <= 2; ++dx) {
                    int xx = x + dx;
                    if (xx < 0 || xx >= 64) continue;
                    int tap = (dy + 2) * 5 + (dx + 2);
                    bf16x8 vv = *(const bf16x8*)&vt[((vyc + dy) * 64 + xx) * HD + d0];
                    const float* wp = &wl[tap * 32 + d0];
                    #pragma unroll
                    for (int dd = 0; dd < 8; ++dd) f[dd] += (float)vv[dd] * wp[dd];
                }
            }
            bf16x8 cv;
            #pragma unroll
            for (int dd = 0; dd < 8; ++dd) cv[dd] = (bf16)f[dd];
            *(bf16x8*)&convres[pix * HD + d0] = cv;
        }
    }
    __syncthreads();

    // ---- Phase C: MFMA attention + merge
    const int col  = lane & 31;
    const int half = lane >> 5;
    const int b = bh / NHEADS, hh = bh % NHEADS;

    // B-fragments from kv (fp32 -> bf16) and broadcast ksum
    bf16x8 bkv0, bkv1, bks0, bks1;
    #pragma unroll
    for (int j = 0; j < 8; ++j) {
        int k = half * 8 + j;
        bkv0[j] = (bf16)kvl[k * 32 + col];
        bkv1[j] = (bf16)kvl[(16 + k) * 32 + col];
        bks0[j] = (bf16)ksl[k];
        bks1[j] = (bf16)ksl[16 + k];
    }

    #pragma unroll
    for (int t = 0; t < 2; ++t) {
        int mt = wid * 2 + t;            // 0..7
        int tok0 = ys * 64 + mt * 32;
        int tokL = tok0 + col;
        bf16x8 a0 = *(const bf16x8*)&qbase[(size_t)tokL * HD + half * 8];
        bf16x8 a1 = *(const bf16x8*)&qbase[(size_t)tokL * HD + 16 + half * 8];
        f32x16 acc = {};
        f32x16 den = {};
        acc = __builtin_amdgcn_mfma_f32_32x32x16_bf16(a0, bkv0, acc, 0, 0, 0);
        acc = __builtin_amdgcn_mfma_f32_32x32x16_bf16(a1, bkv1, acc, 0, 0, 0);
        den = __builtin_amdgcn_mfma_f32_32x32x16_bf16(a0, bks0, den, 0, 0, 0);
        den = __builtin_amdgcn_mfma_f32_32x32x16_bf16(a1, bks1, den, 0, 0, 0);
        #pragma unroll
        for (int r = 0; r < 16; ++r) {
            int row = (r & 3) + 8 * (r >> 2) + 4 * half;
            int pix = mt * 32 + row;             // 0..255
            int tok = ys * 64 + pix;
            float z = 1.f / (den[r] + 1e-6f);
            float val = acc[r] * z + (float)convres[pix * HD + col];
            outp[((size_t)b * SEQ + tok) * CDIM + hh * HD + col] = (bf16)val;
        }
    }
}

// ---------------------------------------------------------------- K4: proj GEMM
// 256x128 tile, 768 blocks, xcd-swizzled.
__global__ __launch_bounds__(256, 2)
void gemm_proj(const bf16* __restrict__ A, const bf16* __restrict__ Wb,
               const float* __restrict__ bias, float* __restrict__ out) {
    __shared__ bf16 sh[384 * 64];
    const int tid  = threadIdx.x;
    const int lane = tid & 63;
    const int wid  = tid >> 6;
    const int blk  = blockIdx.x;
    const int work = (blk & 7) * (768 / 8) + (blk >> 3);
    const int mt   = work / 3;
    const int nt   = work - mt * 3;
    const int m0   = mt * 256;
    const int n0   = nt * 128;
    const int lr   = lane & 15;
    const int lq   = lane >> 4;
    const int srow = lane >> 3;
    const int sc   = lane & 7;

    f32x4 acc[4][8] = {};

    for (int k0 = 0; k0 < CDIM; k0 += 64) {
        #pragma unroll
        for (int it = 0; it < 12; ++it) {
            int rbase = wid * 96 + it * 8;
            int g = rbase + srow;
            int gc = sc ^ (g & 7);
            const bf16* src = (g < 256)
                ? &A [(size_t)(m0 + g) * CDIM + k0 + gc * 8]
                : &Wb[(size_t)(n0 + g - 256) * CDIM + k0 + gc * 8];
            gl_lds16(src, &sh[rbase * 64]);
        }
        __syncthreads();
        #pragma unroll
        for (int ks = 0; ks < 2; ++ks) {
            bf16x8 af[4], bfr[8];
            #pragma unroll
            for (int mi = 0; mi < 4; ++mi) {
                int r = wid * 64 + mi * 16 + lr;
                af[mi] = *(const bf16x8*)&sh[r * 64 + ((ks * 4 + lq) ^ (r & 7)) * 8];
            }
            #pragma unroll
            for (int ni = 0; ni < 8; ++ni) {
                int r = 256 + ni * 16 + lr;
                bfr[ni] = *(const bf16x8*)&sh[r * 64 + ((ks * 4 + lq) ^ (r & 7)) * 8];
            }
            #pragma unroll
            for (int mi = 0; mi < 4; ++mi)
                #pragma unroll
                for (int ni = 0; ni < 8; ++ni)
                    acc[mi][ni] = __builtin_amdgcn_mfma_f32_16x16x32_bf16(
                        af[mi], bfr[ni], acc[mi][ni], 0, 0, 0);
        }
        __syncthreads();
    }

    #pragma unroll
    for (int mi = 0; mi < 4; ++mi) {
        #pragma unroll
        for (int ni = 0; ni < 8; ++ni) {
            int n = n0 + ni * 16 + lr;
            float bv = bias[n];
            #pragma unroll
            for (int r = 0; r < 4; ++r) {
                int m = m0 + wid * 64 + mi * 16 + lq * 4 + r;
                out[(size_t)m * CDIM + n] = acc[mi][ni][r] + bv;
            }
        }
    }
}

// ---------------------------------------------------------------- launch
extern "C" void kernel_launch(void* const* d_in, const int* in_sizes, int n_in,
                              void* d_out, int out_size, void* d_ws, size_t ws_size,
                              hipStream_t stream) {
    const float* x     = (const float*)d_in[0];
    const float* qkvw  = (const float*)d_in[1];
    const float* pos   = (const float*)d_in[2];
    const float* dwcw  = (const float*)d_in[3];
    const float* dwcb  = (const float*)d_in[4];
    const float* projw = (const float*)d_in[5];
    const float* projb = (const float*)d_in[6];
    float* out = (float*)d_out;

    char* ws = (char*)d_ws;
    size_t off = 0;
    auto alloc = [&](size_t bytes) -> void* {
        void* p = ws + off;
        off += (bytes + 255) & ~(size_t)255;
        return p;
    };
    bf16* xb      = (bf16*)alloc((size_t)65536 * CDIM * 2);
    bf16* qkvw_b  = (bf16*)alloc((size_t)3 * CDIM * CDIM * 2);
    bf16* projw_b = (bf16*)alloc((size_t)CDIM * CDIM * 2);
    bf16* qh  = (bf16*)alloc((size_t)BHN * SEQ * HD * 2);
    bf16* khb = (bf16*)alloc((size_t)BHN * SEQ * HD * 2);   // reused as out_pre
    bf16* vh  = (bf16*)alloc((size_t)BHN * SEQ * HD * 2);
    float* kvb   = (float*)alloc((size_t)BHN * KVPARTS * HD * HD * 4);
    float* ksumb = (float*)alloc((size_t)BHN * KVPARTS * HD * 4);

    hipLaunchKernelGGL(convert_in, dim3(2048), dim3(256), 0, stream,
                       x, qkvw, projw, xb, qkvw_b, projw_b);
    hipLaunchKernelGGL(gemm_qkv, dim3(2304), dim3(256), 0, stream,
                       xb, qkvw_b, pos, qh, khb, vh);
    hipLaunchKernelGGL(kv_mfma, dim3(KVPARTS, BHN), dim3(256), 0, stream,
                       khb, vh, kvb, ksumb);
    bf16* outp = khb;   // kh is dead after kv_mfma; reuse as out_pre
    hipLaunchKernelGGL(attn_out, dim3(16, BHN), dim3(256), 0, stream,
                       qh, vh, kvb, ksumb, dwcw, dwcb, outp);
    hipLaunchKernelGGL(gemm_proj, dim3(768), dim3(256), 0, stream,
                       outp, projw_b, projb, out);
}